// Round 1
// baseline (831.475 us; speedup 1.0000x reference)
//
#include <hip/hip_runtime.h>
#include <math.h>

#define NA 20
#define EMBED 64
#define HYPER 512
#define BB 64
#define LL 1024
#define FEA 512
#define SD (NA * FEA)      // 10240
#define KCH 256
#define NCHUNK (SD / KCH)  // 40

// ---------------- Kernel A: gather q_sele, agent_qs, counts, pack masks ----
__global__ __launch_bounds__(256) void kA(const float* __restrict__ qs,
                                          const int* __restrict__ aaw,
                                          const int* __restrict__ aam,
                                          const int* __restrict__ gmask,
                                          const int* __restrict__ mask,
                                          const int* __restrict__ mmask,
                                          float* __restrict__ qsele,
                                          float* __restrict__ aq,
                                          float* __restrict__ cnt,
                                          int* __restrict__ pack) {
  int b = blockIdx.x, t = threadIdx.x;
  __shared__ float aqL[NA], cntL[NA];
  if (t < NA) { aqL[t] = 0.f; cntL[t] = 0.f; }
  __syncthreads();
  for (int l = t; l < LL; l += 256) {
    int idx = b * LL + l;
    int valid = (gmask[idx] != 0) & (mask[idx] != 0);
    int aw = aaw[idx], am = aam[idx];
    int sel = (mmask[idx] != 0) ? am : aw;
    float q = valid ? qs[idx * NA + sel] : 0.f;
    qsele[idx] = q;
    pack[idx] = valid | (aw << 1) | (am << 6);
    if (valid) {
      atomicAdd(&aqL[aw], q);
      atomicAdd(&cntL[aw], 1.f);
      atomicAdd(&cntL[am], 1.f);
    }
  }
  __syncthreads();
  if (t < NA) {
    aq[b * NA + t] = aqL[t];
    cnt[b * NA + t] = cntL[t];
  }
}

// ---------------- Kernel B: segment-sum embeddings (valid rows only) -------
// grid: 64 b x 2 fchunk x 2 lchunk = 256 blocks, 256 threads
__global__ __launch_bounds__(256) void kB(const float* __restrict__ ew,
                                          const float* __restrict__ em,
                                          const int* __restrict__ pack,
                                          float* __restrict__ gpart) {
  int bx = blockIdx.x;
  int b = bx >> 2, fc = (bx >> 1) & 1, lc = bx & 1;
  int t = threadIdx.x;
  __shared__ float acc[NA][256];
#pragma unroll
  for (int a = 0; a < NA; a++) acc[a][t] = 0.f;
  // no syncthreads needed: each thread only ever touches acc[*][t]
  int f = fc * 256 + t;
  int l0 = lc * 512;
  for (int l = l0; l < l0 + 512; ++l) {
    int p = pack[b * LL + l];  // wave-uniform
    if (p & 1) {
      int aw = (p >> 1) & 31, am = (p >> 6) & 31;
      float vw = ew[(size_t)(b * LL + l) * FEA + f];
      float vm = em[(size_t)(b * LL + l) * FEA + f];
      acc[aw][t] += vw;
      acc[am][t] += vm;
    }
  }
#pragma unroll
  for (int a = 0; a < NA; a++)
    gpart[(size_t)((lc * BB + b) * NA + a) * FEA + f] = acc[a][t];
}

// ---------------- Kernel C: states = gsum / counts -------------------------
__global__ __launch_bounds__(256) void kC(const float* __restrict__ gpart,
                                          const float* __restrict__ cnt,
                                          float* __restrict__ states) {
  int idx = blockIdx.x * 256 + threadIdx.x;  // < 64*10240
  int b = idx / SD;
  int r = idx - b * SD;
  int a = r >> 9;
  int f = r & 511;
  float c = cnt[b * NA + a];
  float g = gpart[(size_t)(b * NA + a) * FEA + f] +
            gpart[(size_t)((BB + b) * NA + a) * FEA + f];
  states[idx] = (c > 0.f) ? g / c : 0.f;
}

// ---------------- Kernel D: split-K GEMMs states @ {w1_a,wf_a,hb_w,v1_w} ---
// grid: 40 kchunks x 6 tiles = 240 blocks, 256 threads (4 waves)
__global__ __launch_bounds__(256) void kD(const float* __restrict__ states,
                                          const float* __restrict__ w1a,
                                          const float* __restrict__ wfa,
                                          const float* __restrict__ hbw,
                                          const float* __restrict__ v1w,
                                          float* __restrict__ h1p,
                                          float* __restrict__ hfp,
                                          float* __restrict__ b1p,
                                          float* __restrict__ v1p) {
  int kc = blockIdx.x / 6, tile = blockIdx.x % 6;
  const float* W;
  float* Cp;
  int n0;
  switch (tile) {
    case 0: W = w1a; Cp = h1p; n0 = 0; break;
    case 1: W = w1a; Cp = h1p; n0 = 256; break;
    case 2: W = wfa; Cp = hfp; n0 = 0; break;
    case 3: W = wfa; Cp = hfp; n0 = 256; break;
    case 4: W = hbw; Cp = b1p; n0 = 0; break;
    default: W = v1w; Cp = v1p; n0 = 0; break;
  }
  __shared__ float at[64][64];  // 16 KB: states rows 0..63 x 64 k
  int t = threadIdx.x;
  int l = t & 63, q = t >> 6;

  if (tile < 4) {
    float4 acc[16];
#pragma unroll
    for (int m = 0; m < 16; m++) acc[m] = make_float4(0.f, 0.f, 0.f, 0.f);
    int nb = n0 + l * 4;
    const float4* W4 = (const float4*)W;
    const int N4 = HYPER >> 2;
    for (int kso = 0; kso < 4; ++kso) {
      int k0 = kc * KCH + kso * 64;
      __syncthreads();
#pragma unroll
      for (int it = 0; it < 16; ++it) {
        int idx = it * 256 + t;
        int row = idx >> 6, col = idx & 63;
        at[row][col] = states[row * SD + k0 + col];
      }
      __syncthreads();
#pragma unroll
      for (int ks4 = 0; ks4 < 16; ++ks4) {
        int k = k0 + ks4 * 4;
        float4 w0 = W4[(k + 0) * N4 + (nb >> 2)];
        float4 w1 = W4[(k + 1) * N4 + (nb >> 2)];
        float4 w2 = W4[(k + 2) * N4 + (nb >> 2)];
        float4 w3 = W4[(k + 3) * N4 + (nb >> 2)];
#pragma unroll
        for (int m = 0; m < 16; m++) {
          const float4 av = *(const float4*)&at[q * 16 + m][ks4 * 4];
          acc[m].x += av.x * w0.x + av.y * w1.x + av.z * w2.x + av.w * w3.x;
          acc[m].y += av.x * w0.y + av.y * w1.y + av.z * w2.y + av.w * w3.y;
          acc[m].z += av.x * w0.z + av.y * w1.z + av.z * w2.z + av.w * w3.z;
          acc[m].w += av.x * w0.w + av.y * w1.w + av.z * w2.w + av.w * w3.w;
        }
      }
    }
#pragma unroll
    for (int m = 0; m < 16; m++) {
      int mg = q * 16 + m;
      *(float4*)&Cp[(size_t)(kc * BB + mg) * HYPER + nb] = acc[m];
    }
  } else {
    float acc[16];
#pragma unroll
    for (int m = 0; m < 16; m++) acc[m] = 0.f;
    for (int kso = 0; kso < 4; ++kso) {
      int k0 = kc * KCH + kso * 64;
      __syncthreads();
#pragma unroll
      for (int it = 0; it < 16; ++it) {
        int idx = it * 256 + t;
        int row = idx >> 6, col = idx & 63;
        at[row][col] = states[row * SD + k0 + col];
      }
      __syncthreads();
#pragma unroll
      for (int ks4 = 0; ks4 < 16; ++ks4) {
        int k = k0 + ks4 * 4;
        float w0 = W[(k + 0) * EMBED + l];
        float w1 = W[(k + 1) * EMBED + l];
        float w2 = W[(k + 2) * EMBED + l];
        float w3 = W[(k + 3) * EMBED + l];
#pragma unroll
        for (int m = 0; m < 16; m++) {
          const float4 av = *(const float4*)&at[q * 16 + m][ks4 * 4];
          acc[m] += av.x * w0 + av.y * w1 + av.z * w2 + av.w * w3;
        }
      }
    }
#pragma unroll
    for (int m = 0; m < 16; m++) {
      int mg = q * 16 + m;
      Cp[(size_t)(kc * BB + mg) * EMBED + l] = acc[m];
    }
  }
}

// ---------------- Kernel E: per-batch epilogue -----------------------------
__global__ __launch_bounds__(256) void kE(
    const float* __restrict__ h1p, const float* __restrict__ hfp,
    const float* __restrict__ b1p, const float* __restrict__ v1p,
    const float* __restrict__ aqg, const float* __restrict__ b1a,
    const float* __restrict__ bfa, const float* __restrict__ hbb,
    const float* __restrict__ v1b, const float* __restrict__ w1b,
    const float* __restrict__ b1bb, const float* __restrict__ wfb,
    const float* __restrict__ bfb, const float* __restrict__ v2w,
    const float* __restrict__ v2b, float* __restrict__ out) {
  int b = blockIdx.x, t = threadIdx.x;
  __shared__ float h1s[HYPER], hfs[HYPER], b1s[EMBED], v1s[EMBED];
  __shared__ float aqL[NA], mixL[EMBED], wfv[EMBED];
  for (int c = t; c < HYPER; c += 256) {
    float s = 0.f, s2 = 0.f;
    for (int kc = 0; kc < NCHUNK; ++kc) {
      s += h1p[(size_t)(kc * BB + b) * HYPER + c];
      s2 += hfp[(size_t)(kc * BB + b) * HYPER + c];
    }
    s += b1a[c];
    h1s[c] = s > 0.f ? s : 0.f;
    s2 += bfa[c];
    hfs[c] = s2 > 0.f ? s2 : 0.f;
  }
  if (t < EMBED) {
    float s = 0.f, s2 = 0.f;
    for (int kc = 0; kc < NCHUNK; ++kc) {
      s += b1p[(size_t)(kc * BB + b) * EMBED + t];
      s2 += v1p[(size_t)(kc * BB + b) * EMBED + t];
    }
    b1s[t] = s + hbb[t];
    s2 += v1b[t];
    v1s[t] = s2 > 0.f ? s2 : 0.f;
    mixL[t] = 0.f;
  }
  if (t < NA) aqL[t] = aqg[b * NA + t];
  __syncthreads();
  for (int c = t; c < 1280 + EMBED; c += 256) {
    if (c < 1280) {
      float dot = 0.f;
      for (int h = 0; h < HYPER; ++h) dot += h1s[h] * w1b[h * 1280 + c];
      float v = fabsf(dot + b1bb[c]);
      atomicAdd(&mixL[c & 63], aqL[c >> 6] * v);
    } else {
      int e = c - 1280;
      float dot = 0.f;
      for (int h = 0; h < HYPER; ++h) dot += hfs[h] * wfb[h * EMBED + e];
      wfv[e] = fabsf(dot + bfb[e]);
    }
  }
  __syncthreads();
  if (t == 0) {
    float bf = v2b[0];
    for (int e = 0; e < EMBED; e++) bf += v1s[e] * v2w[e];
    float qt = 0.f;
    for (int e = 0; e < EMBED; e++) {
      float x = mixL[e] + b1s[e];
      x = x > 0.f ? x : expm1f(x);
      qt += x * wfv[e];
    }
    out[b] = qt + bf;
  }
}

extern "C" void kernel_launch(void* const* d_in, const int* in_sizes, int n_in,
                              void* d_out, int out_size, void* d_ws,
                              size_t ws_size, hipStream_t stream) {
  const float* qs_wt = (const float*)d_in[0];
  const int* aa_wt = (const int*)d_in[1];
  const int* aa_mut = (const int*)d_in[2];
  const int* agent_mask = (const int*)d_in[3];
  const int* mask = (const int*)d_in[4];
  const int* mutation_mask = (const int*)d_in[5];
  const float* emb_wt = (const float*)d_in[6];
  const float* emb_mut = (const float*)d_in[7];
  const float* w1_a = (const float*)d_in[8];
  const float* b1_a = (const float*)d_in[9];
  const float* w1_b = (const float*)d_in[10];
  const float* b1_b = (const float*)d_in[11];
  const float* hb_w = (const float*)d_in[12];
  const float* hb_b = (const float*)d_in[13];
  const float* wf_a = (const float*)d_in[14];
  const float* bf_a = (const float*)d_in[15];
  const float* wf_b = (const float*)d_in[16];
  const float* bf_b = (const float*)d_in[17];
  const float* v1_w = (const float*)d_in[18];
  const float* v1_b = (const float*)d_in[19];
  const float* v2_w = (const float*)d_in[20];
  const float* v2_b = (const float*)d_in[21];

  char* ws = (char*)d_ws;
  // workspace layout (bytes)
  float* aq = (float*)(ws + 0);                  // 64*20*4      = 5120
  float* cnt = (float*)(ws + 5120);              // 5120
  int* pack = (int*)(ws + 10240);                // 65536*4      = 262144
  float* gpart = (float*)(ws + 272384);          // 2*64*20*512*4= 5242880
  float* states = (float*)(ws + 5515264);        // 64*10240*4   = 2621440
  float* h1p = (float*)(ws + 8136704);           // 40*64*512*4  = 5242880
  float* hfp = (float*)(ws + 13379584);          // 5242880
  float* b1p = (float*)(ws + 18622464);          // 40*64*64*4   = 655360
  float* v1p = (float*)(ws + 19277824);          // 655360  (end ~19.0 MiB)

  float* out = (float*)d_out;       // [0:64]  q_tot
  float* qsele = out + 64;          // [64:65600] q_sele

  kA<<<64, 256, 0, stream>>>(qs_wt, aa_wt, aa_mut, agent_mask, mask,
                             mutation_mask, qsele, aq, cnt, pack);
  kB<<<256, 256, 0, stream>>>(emb_wt, emb_mut, pack, gpart);
  kC<<<2560, 256, 0, stream>>>(gpart, cnt, states);
  kD<<<240, 256, 0, stream>>>(states, w1_a, wf_a, hb_w, v1_w, h1p, hfp, b1p,
                              v1p);
  kE<<<64, 256, 0, stream>>>(h1p, hfp, b1p, v1p, aq, b1_a, bf_a, hb_b, v1_b,
                             w1_b, b1_b, wf_b, bf_b, v2_w, v2_b, out);
}

// Round 3
// 428.086 us; speedup vs baseline: 1.9423x; 1.9423x over previous
//
#include <hip/hip_runtime.h>
#include <math.h>

#define NA 20
#define EMBED 64
#define HYPER 512
#define BB 64
#define LL 1024
#define FEA 512
#define SD (NA * FEA)      // 10240
#define KCH 256
#define NCHUNK (SD / KCH)  // 40
#define LCH 4              // kB l-chunks

// ---------------- Kernel A: gather q_sele, agent_qs, counts, pack masks ----
// grid 256 = 64 b x 4 lc, 256 threads (1 l each)
__global__ __launch_bounds__(256) void kA(const float* __restrict__ qs,
                                          const int* __restrict__ aaw,
                                          const int* __restrict__ aam,
                                          const int* __restrict__ gmask,
                                          const int* __restrict__ mask,
                                          const int* __restrict__ mmask,
                                          float* __restrict__ qsele,
                                          float* __restrict__ aq,
                                          float* __restrict__ cnt,
                                          int* __restrict__ pack) {
  int b = blockIdx.x >> 2, lc = blockIdx.x & 3, t = threadIdx.x;
  __shared__ float aqL[NA], cntL[NA];
  if (t < NA) { aqL[t] = 0.f; cntL[t] = 0.f; }
  __syncthreads();
  int l = lc * 256 + t;
  int idx = b * LL + l;
  int valid = (gmask[idx] != 0) & (mask[idx] != 0);
  int aw = aaw[idx], am = aam[idx];
  int sel = (mmask[idx] != 0) ? am : aw;
  float q = valid ? qs[idx * NA + sel] : 0.f;
  qsele[idx] = q;
  pack[idx] = valid | (aw << 1) | (am << 6);
  if (valid) {
    atomicAdd(&aqL[aw], q);
    atomicAdd(&cntL[aw], 1.f);
    atomicAdd(&cntL[am], 1.f);
  }
  __syncthreads();
  if (t < NA) {
    if (aqL[t] != 0.f) atomicAdd(&aq[b * NA + t], aqL[t]);
    if (cntL[t] != 0.f) atomicAdd(&cnt[b * NA + t], cntL[t]);
  }
}

// ---------------- Kernel B: segment-sum embeddings (valid rows only) -------
// grid: 64 b x 2 fc x 4 lc = 512 blocks, 256 threads
__global__ __launch_bounds__(256) void kB(const float* __restrict__ ew,
                                          const float* __restrict__ em,
                                          const int* __restrict__ pack,
                                          float* __restrict__ gpart) {
  int bx = blockIdx.x;
  int b = bx >> 3, fc = (bx >> 2) & 1, lc = bx & 3;
  int t = threadIdx.x;
  __shared__ float acc[NA][256];
#pragma unroll
  for (int a = 0; a < NA; a++) acc[a][t] = 0.f;
  // each thread only touches acc[*][t]: no sync needed
  int f = fc * 256 + t;
  int l0 = lc * 256;
  for (int l = l0; l < l0 + 256; ++l) {
    int p = pack[b * LL + l];  // wave-uniform
    if (p & 1) {
      int aw = (p >> 1) & 31, am = (p >> 6) & 31;
      acc[aw][t] += ew[(size_t)(b * LL + l) * FEA + f];
      acc[am][t] += em[(size_t)(b * LL + l) * FEA + f];
    }
  }
#pragma unroll
  for (int a = 0; a < NA; a++)
    gpart[(size_t)((lc * BB + b) * NA + a) * FEA + f] = acc[a][t];
}

// ---------------- Kernel C: states = (sum over lc slices) / counts --------
__global__ __launch_bounds__(256) void kC(const float* __restrict__ gpart,
                                          const float* __restrict__ cnt,
                                          float* __restrict__ states) {
  int idx = blockIdx.x * 256 + threadIdx.x;  // < 64*10240
  int b = idx / SD;
  int r = idx - b * SD;
  int a = r >> 9;
  float c = cnt[b * NA + a];
  size_t base = (size_t)(b * NA) * FEA + r;  // == (b*NA+a)*FEA + f
  const size_t slice = (size_t)BB * NA * FEA;
  float g = gpart[base] + gpart[base + slice] + gpart[base + 2 * slice] +
            gpart[base + 3 * slice];
  states[idx] = (c > 0.f) ? g / c : 0.f;
}

// ---------------- Kernel D: split-K GEMMs states @ {w1_a,wf_a,hb_w,v1_w} ---
// grid: 40 kchunks x 18 tiles = 720 blocks, 256 threads
// per-thread: 4 m-rows x 4 n-cols (float4), 16 FMA per ds_read_b128
__global__ __launch_bounds__(256) void kD(const float* __restrict__ states,
                                          const float* __restrict__ w1a,
                                          const float* __restrict__ wfa,
                                          const float* __restrict__ hbw,
                                          const float* __restrict__ v1w,
                                          float* __restrict__ h1p,
                                          float* __restrict__ hfp,
                                          float* __restrict__ b1p,
                                          float* __restrict__ v1p) {
  int kc = blockIdx.x / 18, tile = blockIdx.x % 18;
  const float* W;
  float* Cp;
  int Nw, n0;
  if (tile < 8) { W = w1a; Cp = h1p; Nw = HYPER; n0 = tile * 64; }
  else if (tile < 16) { W = wfa; Cp = hfp; Nw = HYPER; n0 = (tile - 8) * 64; }
  else if (tile == 16) { W = hbw; Cp = b1p; Nw = EMBED; n0 = 0; }
  else { W = v1w; Cp = v1p; Nw = EMBED; n0 = 0; }

  __shared__ float at[64][132];  // padded: rows 4 banks apart
  int t = threadIdx.x;
  int n4 = t & 15, mq = t >> 4;  // n = n0 + n4*4.., rows mq*4..mq*4+3
  float4 acc[4];
#pragma unroll
  for (int mi = 0; mi < 4; mi++) acc[mi] = make_float4(0.f, 0.f, 0.f, 0.f);

  for (int kso = 0; kso < 2; ++kso) {
    int k0 = kc * KCH + kso * 128;
    __syncthreads();
#pragma unroll
    for (int it = 0; it < 8; ++it) {
      int idx = it * 256 + t;
      int row = idx >> 5, c4 = idx & 31;
      *(float4*)&at[row][c4 * 4] =
          *(const float4*)&states[(size_t)row * SD + k0 + c4 * 4];
    }
    __syncthreads();
#pragma unroll 8
    for (int k4 = 0; k4 < 32; ++k4) {
      int kk = k4 * 4;
      const float* Wb = W + (size_t)(k0 + kk) * Nw + n0 + (n4 << 2);
      float4 w0 = *(const float4*)(Wb);
      float4 w1 = *(const float4*)(Wb + Nw);
      float4 w2 = *(const float4*)(Wb + 2 * Nw);
      float4 w3 = *(const float4*)(Wb + 3 * Nw);
#pragma unroll
      for (int mi = 0; mi < 4; mi++) {
        float4 av = *(const float4*)&at[mq * 4 + mi][kk];
        acc[mi].x += av.x * w0.x + av.y * w1.x + av.z * w2.x + av.w * w3.x;
        acc[mi].y += av.x * w0.y + av.y * w1.y + av.z * w2.y + av.w * w3.y;
        acc[mi].z += av.x * w0.z + av.y * w1.z + av.z * w2.z + av.w * w3.z;
        acc[mi].w += av.x * w0.w + av.y * w1.w + av.z * w2.w + av.w * w3.w;
      }
    }
  }
#pragma unroll
  for (int mi = 0; mi < 4; mi++) {
    int m = mq * 4 + mi;
    *(float4*)&Cp[(size_t)(kc * BB + m) * Nw + n0 + (n4 << 2)] = acc[mi];
  }
}

// ---------------- Kernel E1: reduce split-K partials + bias + relu ---------
// grid: 256 (h1/hf: 64b x 4cc, c=cc*128+t) + 64 (b1/v1) = 320 blocks, 128 thr
__global__ __launch_bounds__(128) void kE1(const float* __restrict__ h1p,
                                           const float* __restrict__ hfp,
                                           const float* __restrict__ b1p,
                                           const float* __restrict__ v1p,
                                           const float* __restrict__ b1a,
                                           const float* __restrict__ bfa,
                                           const float* __restrict__ hbb,
                                           const float* __restrict__ v1b,
                                           float* __restrict__ h1,
                                           float* __restrict__ hf,
                                           float* __restrict__ b1s,
                                           float* __restrict__ v1r) {
  int bx = blockIdx.x, t = threadIdx.x;
  if (bx < 256) {
    int b = bx >> 2, c = (bx & 3) * 128 + t;
    float s1 = 0.f, s2 = 0.f;
#pragma unroll 4
    for (int kc = 0; kc < NCHUNK; ++kc) {
      s1 += h1p[(size_t)(kc * BB + b) * HYPER + c];
      s2 += hfp[(size_t)(kc * BB + b) * HYPER + c];
    }
    s1 += b1a[c];
    s2 += bfa[c];
    h1[b * HYPER + c] = s1 > 0.f ? s1 : 0.f;
    hf[b * HYPER + c] = s2 > 0.f ? s2 : 0.f;
  } else {
    int b = bx - 256;
    const float* P = (t < 64) ? b1p : v1p;
    int c = t & 63;
    float s = 0.f;
#pragma unroll 4
    for (int kc = 0; kc < NCHUNK; ++kc)
      s += P[(size_t)(kc * BB + b) * EMBED + c];
    if (t < 64) b1s[b * EMBED + c] = s + hbb[c];
    else v1r[b * EMBED + c] = fmaxf(s + v1b[c], 0.f);
  }
}

// ---------------- Kernel E2: second-layer GEMMs ----------------------------
// grid 64 b x 21 tiles = 1344 blocks, 64 threads
// a<20: mixp[b][a][e] = aq[b][a]*|h1[b]@w1b[:,a*64+e] + b1_b|
// a==20: wfq[b][e]    = |hf[b]@wfb[:,e] + bfb|
__global__ __launch_bounds__(64) void kE2(const float* __restrict__ h1,
                                          const float* __restrict__ hf,
                                          const float* __restrict__ aq,
                                          const float* __restrict__ w1b,
                                          const float* __restrict__ b1bb,
                                          const float* __restrict__ wfb,
                                          const float* __restrict__ bfb,
                                          float* __restrict__ mixp,
                                          float* __restrict__ wfq) {
  int b = blockIdx.x / 21, a = blockIdx.x % 21;
  int t = threadIdx.x;
  __shared__ float hs[HYPER];
  const float* src = (a < 20) ? (h1 + b * HYPER) : (hf + b * HYPER);
#pragma unroll
  for (int i = 0; i < 8; ++i) hs[t + i * 64] = src[t + i * 64];
  __syncthreads();
  float dot = 0.f;
  if (a < 20) {
    const float* Wc = w1b + a * 64 + t;
#pragma unroll 8
    for (int h = 0; h < HYPER; ++h) dot += hs[h] * Wc[(size_t)h * 1280];
    mixp[(size_t)(b * NA + a) * EMBED + t] =
        aq[b * NA + a] * fabsf(dot + b1bb[a * 64 + t]);
  } else {
    const float* Wc = wfb + t;
#pragma unroll 8
    for (int h = 0; h < HYPER; ++h) dot += hs[h] * Wc[(size_t)h * EMBED];
    wfq[b * EMBED + t] = fabsf(dot + bfb[t]);
  }
}

// ---------------- Kernel E3: finisher --------------------------------------
// grid 64, 64 threads (1 wave)
__global__ __launch_bounds__(64) void kE3(const float* __restrict__ mixp,
                                          const float* __restrict__ b1s,
                                          const float* __restrict__ v1r,
                                          const float* __restrict__ wfq,
                                          const float* __restrict__ v2w,
                                          const float* __restrict__ v2b,
                                          float* __restrict__ out) {
  int b = blockIdx.x, t = threadIdx.x;
  float s = 0.f;
#pragma unroll
  for (int a = 0; a < NA; ++a) s += mixp[(size_t)(b * NA + a) * EMBED + t];
  float x = s + b1s[b * EMBED + t];
  x = x > 0.f ? x : expm1f(x);
  float val = x * wfq[b * EMBED + t] + v1r[b * EMBED + t] * v2w[t];
#pragma unroll
  for (int off = 32; off >= 1; off >>= 1) val += __shfl_xor(val, off, 64);
  if (t == 0) out[b] = val + v2b[0];
}

extern "C" void kernel_launch(void* const* d_in, const int* in_sizes, int n_in,
                              void* d_out, int out_size, void* d_ws,
                              size_t ws_size, hipStream_t stream) {
  const float* qs_wt = (const float*)d_in[0];
  const int* aa_wt = (const int*)d_in[1];
  const int* aa_mut = (const int*)d_in[2];
  const int* agent_mask = (const int*)d_in[3];
  const int* mask = (const int*)d_in[4];
  const int* mutation_mask = (const int*)d_in[5];
  const float* emb_wt = (const float*)d_in[6];
  const float* emb_mut = (const float*)d_in[7];
  const float* w1_a = (const float*)d_in[8];
  const float* b1_a = (const float*)d_in[9];
  const float* w1_b = (const float*)d_in[10];
  const float* b1_b = (const float*)d_in[11];
  const float* hb_w = (const float*)d_in[12];
  const float* hb_b = (const float*)d_in[13];
  const float* wf_a = (const float*)d_in[14];
  const float* bf_a = (const float*)d_in[15];
  const float* wf_b = (const float*)d_in[16];
  const float* bf_b = (const float*)d_in[17];
  const float* v1_w = (const float*)d_in[18];
  const float* v1_b = (const float*)d_in[19];
  const float* v2_w = (const float*)d_in[20];
  const float* v2_b = (const float*)d_in[21];

  char* ws = (char*)d_ws;
  // workspace layout (bytes); h1p/hfp alias gpart (dead after kC)
  float* aq = (float*)(ws + 0);               // 5120
  float* cnt = (float*)(ws + 5120);           // 5120
  int* pack = (int*)(ws + 10240);             // 262144 -> 272384
  float* gpart = (float*)(ws + 272384);       // 4*64*20*512*4 = 10485760 -> 10758144
  float* h1p = (float*)(ws + 272384);         // alias gpart: 5242880 -> 5515264
  float* hfp = (float*)(ws + 5515264);        // alias gpart: 5242880 -> 10758144
  float* states = (float*)(ws + 10758144);    // 2621440 -> 13379584
  float* b1p = (float*)(ws + 13379584);       // 655360 -> 14034944
  float* v1p = (float*)(ws + 14034944);       // 655360 -> 14690304
  float* h1 = (float*)(ws + 14690304);        // 131072 -> 14821376
  float* hf = (float*)(ws + 14821376);        // 131072 -> 14952448
  float* b1s = (float*)(ws + 14952448);       // 16384 -> 14968832
  float* v1r = (float*)(ws + 14968832);       // 16384 -> 14985216
  float* mixp = (float*)(ws + 14985216);      // 327680 -> 15312896
  float* wfq = (float*)(ws + 15312896);       // 16384 -> 15329280

  float* out = (float*)d_out;  // [0:64] q_tot
  float* qsele = out + 64;     // [64:65600] q_sele

  hipMemsetAsync(ws, 0, 10240, stream);  // zero aq + cnt
  kA<<<256, 256, 0, stream>>>(qs_wt, aa_wt, aa_mut, agent_mask, mask,
                              mutation_mask, qsele, aq, cnt, pack);
  kB<<<512, 256, 0, stream>>>(emb_wt, emb_mut, pack, gpart);
  kC<<<2560, 256, 0, stream>>>(gpart, cnt, states);
  kD<<<720, 256, 0, stream>>>(states, w1_a, wf_a, hb_w, v1_w, h1p, hfp, b1p,
                              v1p);
  kE1<<<320, 128, 0, stream>>>(h1p, hfp, b1p, v1p, b1_a, bf_a, hb_b, v1_b, h1,
                               hf, b1s, v1r);
  kE2<<<1344, 64, 0, stream>>>(h1, hf, aq, w1_b, b1_b, wf_b, bf_b, mixp, wfq);
  kE3<<<64, 64, 0, stream>>>(mixp, b1s, v1r, wfq, v2_w, v2_b, out);
}